// Round 17
// baseline (414.757 us; speedup 1.0000x reference)
//
#include <hip/hip_runtime.h>
#include <hip/hip_bf16.h>

// Problem constants
#define NB 4
#define NT 256
#define NU 100
#define NH 512      // H_ENC = H_DEC = 512
#define NI 512      // INNER
#define NV 1024     // VOCAB
#define MROWS (NB * NT * NU)   // 102400 joint rows

typedef __attribute__((ext_vector_type(16))) float f32x16;
typedef __attribute__((ext_vector_type(8))) __bf16 bf16x8;

// round-to-nearest-even f32 -> bf16 bits
static __device__ __forceinline__ unsigned int f2bf(float f) {
  unsigned int u = __float_as_uint(f);
  return (u + 0x7FFFu + ((u >> 16) & 1u)) >> 16;
}

// tanh(x) = 1 - 2/(1+e^{2x})
static __device__ __forceinline__ float fast_tanh(float x) {
  float e = __expf(2.f * x);
  return 1.f - 2.f * __builtin_amdgcn_rcpf(1.f + e);
}

// packed RNE f32x2 -> bf16x2 (single instruction)
static __device__ __forceinline__ unsigned int cvt_pk_bf16(float lo, float hi) {
  unsigned int r;
  asm("v_cvt_pk_bf16_f32 %0, %1, %2" : "=v"(r) : "v"(lo), "v"(hi));
  return r;
}

// ---------------------------------------------------------------------------
// Merged prep kernel. Grid (55, 8):
//  bx < 23: projections  pe[r][i] = enc[r][:] . W1[i][0:512]     (r < 1024)
//                        pd[r][i] = dec[r][:] . W1[i][512:1024]  (r < 400)
//  bx >= 23: W2 f32 -> bf16 pre-fragged for 32x32x16 B operands:
//    chunk c (16B) = [np 4][ks 32][ntl 8][lane 64]:
//      col = np*256 + ntl*32 + (lane&31),  k = ks*16 + (lane>>5)*8
// ---------------------------------------------------------------------------
__global__ __launch_bounds__(256) void prep_kernel(
    const float* __restrict__ enc, const float* __restrict__ dec,
    const float* __restrict__ W1, const float* __restrict__ W2,
    float* __restrict__ pe, float* __restrict__ pd,
    unsigned short* __restrict__ w2g) {
  const int bx = blockIdx.x;
  const int tx = threadIdx.x;
  if (bx >= 23) {
    int c = ((bx - 23) * 8 + blockIdx.y) * 256 + tx;  // 65536 chunks
    int lane = c & 63, ntl = (c >> 6) & 7, ks = (c >> 9) & 31, np = c >> 14;
    int col = np * 256 + ntl * 32 + (lane & 31);
    int k = ks * 16 + (lane >> 5) * 8;
    const float* src = W2 + (size_t)col * NI + k;
    float4 a = *(const float4*)src;
    float4 b = *(const float4*)(src + 4);
    uint4 o;
    o.x = f2bf(a.x) | (f2bf(a.y) << 16);
    o.y = f2bf(a.z) | (f2bf(a.w) << 16);
    o.z = f2bf(b.x) | (f2bf(b.y) << 16);
    o.w = f2bf(b.z) | (f2bf(b.w) << 16);
    *(uint4*)(w2g + (size_t)c * 8) = o;
    return;
  }
  __shared__ float As[64][17];
  __shared__ float Bs[64][17];
  const float* A;
  float* P;
  int Mrows, colOff, row0;
  if (bx < 16) { A = enc; P = pe; Mrows = NB * NT; colOff = 0;  row0 = bx * 64; }
  else         { A = dec; P = pd; Mrows = NB * NU; colOff = NH; row0 = (bx - 16) * 64; }
  const int col0 = blockIdx.y * 64;
  const int tr = tx >> 4, tc = tx & 15;
  const int lr = tx >> 2, lc = (tx & 3) * 4;
  float acc[4][4] = {};
  for (int k0 = 0; k0 < NH; k0 += 16) {
    float4 av = make_float4(0.f, 0.f, 0.f, 0.f);
    if (row0 + lr < Mrows)
      av = *(const float4*)(A + (size_t)(row0 + lr) * NH + k0 + lc);
    float4 bv = *(const float4*)(W1 + (size_t)(col0 + lr) * (NH + NH) + colOff + k0 + lc);
    As[lr][lc] = av.x; As[lr][lc + 1] = av.y; As[lr][lc + 2] = av.z; As[lr][lc + 3] = av.w;
    Bs[lr][lc] = bv.x; Bs[lr][lc + 1] = bv.y; Bs[lr][lc + 2] = bv.z; Bs[lr][lc + 3] = bv.w;
    __syncthreads();
#pragma unroll
    for (int kk = 0; kk < 16; ++kk) {
      float a4[4], b4[4];
#pragma unroll
      for (int i = 0; i < 4; ++i) { a4[i] = As[tr * 4 + i][kk]; b4[i] = Bs[tc * 4 + i][kk]; }
#pragma unroll
      for (int i = 0; i < 4; ++i)
#pragma unroll
        for (int j = 0; j < 4; ++j) acc[i][j] = fmaf(a4[i], b4[j], acc[i][j]);
    }
    __syncthreads();
  }
#pragma unroll
  for (int i = 0; i < 4; ++i) {
    int r = row0 + tr * 4 + i;
    if (r < Mrows) {
#pragma unroll
      for (int j = 0; j < 4; ++j)
        P[(size_t)r * NI + col0 + tc * 4 + j] = acc[i][j];
    }
  }
}

// ---------------------------------------------------------------------------
// Fused joint GEMM: barrier-free K-loop, tanh once, TALL wave tiles.
// Block: 512 thr / 8 waves side-by-side in N; block = 128 rows x full vocab.
// Wave tile: 128 rows x 32 cols = 4 stacked 32x32 acc tiles (4 x f32x16).
//   -> aggregate B-fragment L2 traffic = 800 MB (4x less than 32-row tiles).
// Phase 0: A panel (128 x 512) = tanh(pe+pd+b1) -> 128 KB LDS, granule
//   swizzle g8 ^ (row&7). ONE barrier total.
// K-loop: 128 steps of K=16 (np = g>>5 panel, ks = g&31), ring-4 register
//   B pipeline: STEP(sX, g) THEN LOADB(sX, g+4) — use-then-reload (the
//   R16 bug was reload-before-use, clobbering the set). Re-use trails the
//   reload by 3 steps = 12 MFMA + 3 ds_read (~L2 latency).
// Epilogue per panel (ks==31): +b2, fp32 stores (128B/half-wave segments),
//   re-zero acc. C/D map: col=lane&31, row=(r&3)+8*(r>>2)+4*(lane>>5)
//   [validated by R15 pass].
// ---------------------------------------------------------------------------
__global__ __launch_bounds__(512, 2) void fused_joint_kernel(
    const float* __restrict__ pe, const float* __restrict__ pd,
    const float* __restrict__ b1, const unsigned short* __restrict__ w2g,
    const float* __restrict__ b2, float* __restrict__ out) {
  __shared__ unsigned char ldsA[131072];   // 128 rows x 512 k bf16, swizzled
  const int tx = threadIdx.x;
  const int R0 = blockIdx.x * 128;
  const int lane = tx & 63, wid = tx >> 6;  // wave owns cols wid*32..+31
  const int l31 = lane & 31, lh = lane >> 5;

  // B frag base: chunk = (G*8 + wid)*64 + lane  (16B chunks)
  const unsigned char* w2p = (const unsigned char*)w2g;
  const unsigned char* bBase = w2p + ((size_t)(wid * 64 + lane)) * 16;

#define LOADB(SET, G) do {                                                    \
    SET = *(const bf16x8*)(bBase + ((size_t)(G) << 13));                      \
  } while (0)

  bf16x8 s0, s1, s2, s3;
  LOADB(s0, 0); LOADB(s1, 1); LOADB(s2, 2); LOADB(s3, 3);  // thru phase 0

  // ---- Phase 0: A panel (128 x 512) = tanh(pe+pd+b1) -> ldsA ----
#pragma unroll 2
  for (int pass = 0; pass < 16; ++pass) {
    int idx = pass * 512 + tx;             // 8192 granules of 8 elems
    int row = idx >> 6;                    // 0..127
    int g8 = idx & 63;                     // granule within row
    int i0 = g8 * 8;
    int grow = R0 + row;
    int b = grow / (NT * NU);
    int rem = grow - b * (NT * NU);
    int t = rem / NU;
    int u = rem - t * NU;
    const float* peP = pe + (size_t)(b * NT + t) * NI + i0;
    const float* pdP = pd + (size_t)(b * NU + u) * NI + i0;
    float4 p0 = *(const float4*)peP, p1 = *(const float4*)(peP + 4);
    float4 q0 = *(const float4*)pdP, q1 = *(const float4*)(pdP + 4);
    float4 c0 = *(const float4*)(b1 + i0), c1 = *(const float4*)(b1 + i0 + 4);
    uint4 pk;
    pk.x = cvt_pk_bf16(fast_tanh(p0.x + q0.x + c0.x), fast_tanh(p0.y + q0.y + c0.y));
    pk.y = cvt_pk_bf16(fast_tanh(p0.z + q0.z + c0.z), fast_tanh(p0.w + q0.w + c0.w));
    pk.z = cvt_pk_bf16(fast_tanh(p1.x + q1.x + c1.x), fast_tanh(p1.y + q1.y + c1.y));
    pk.w = cvt_pk_bf16(fast_tanh(p1.z + q1.z + c1.z), fast_tanh(p1.w + q1.w + c1.w));
    *(uint4*)(ldsA + row * 1024 + ((g8 ^ (row & 7)) << 4)) = pk;
  }
  __syncthreads();                         // the ONLY barrier

  f32x16 acc[4];
#pragma unroll
  for (int m = 0; m < 4; ++m)
#pragma unroll
    for (int z = 0; z < 16; ++z) acc[m][z] = 0.f;

  // A frag: row = m*32 + l31; addr = row*1024 + ((gi ^ (row&7))<<4),
  // gi = (g&31)*2 + lh;  row&7 == l31&7 for all m (32 % 8 == 0).
  const int aBase = l31 * 1024;
  const int rx = l31 & 7;

#define STEP(SET, G) do {                                                     \
    const int ks_ = (G) & 31;                                                 \
    const int so_ = (((ks_ * 2 + lh) ^ rx) << 4);                             \
    bf16x8 af0_ = *(const bf16x8*)(ldsA + aBase + so_);                       \
    bf16x8 af1_ = *(const bf16x8*)(ldsA + aBase + 32768 + so_);               \
    bf16x8 af2_ = *(const bf16x8*)(ldsA + aBase + 65536 + so_);               \
    bf16x8 af3_ = *(const bf16x8*)(ldsA + aBase + 98304 + so_);               \
    __builtin_amdgcn_s_setprio(1);                                            \
    acc[0] = __builtin_amdgcn_mfma_f32_32x32x16_bf16(af0_, SET, acc[0], 0, 0, 0); \
    acc[1] = __builtin_amdgcn_mfma_f32_32x32x16_bf16(af1_, SET, acc[1], 0, 0, 0); \
    acc[2] = __builtin_amdgcn_mfma_f32_32x32x16_bf16(af2_, SET, acc[2], 0, 0, 0); \
    acc[3] = __builtin_amdgcn_mfma_f32_32x32x16_bf16(af3_, SET, acc[3], 0, 0, 0); \
    __builtin_amdgcn_s_setprio(0);                                            \
    if (ks_ == 31) {                                                          \
      const int np_ = (G) >> 5;                                               \
      int col_ = np_ * 256 + wid * 32 + l31;                                  \
      float bb_ = b2[col_];                                                   \
      _Pragma("unroll")                                                       \
      for (int m_ = 0; m_ < 4; ++m_) {                                        \
        _Pragma("unroll")                                                     \
        for (int r_ = 0; r_ < 16; ++r_) {                                     \
          int grow_ = R0 + m_ * 32 + (r_ & 3) + 8 * (r_ >> 2) + 4 * lh;       \
          out[(size_t)grow_ * NV + col_] = acc[m_][r_] + bb_;                 \
          acc[m_][r_] = 0.f;                                                  \
        }                                                                     \
      }                                                                       \
    }                                                                         \
  } while (0)

  for (int g = 0; g < 128; g += 4) {
    STEP(s0, g);     if (g + 4 < 128) LOADB(s0, g + 4);   // use THEN reload
    STEP(s1, g + 1); if (g + 5 < 128) LOADB(s1, g + 5);
    STEP(s2, g + 2); if (g + 6 < 128) LOADB(s2, g + 6);
    STEP(s3, g + 3); if (g + 7 < 128) LOADB(s3, g + 7);
  }
#undef STEP
#undef LOADB
}

extern "C" void kernel_launch(void* const* d_in, const int* in_sizes, int n_in,
                              void* d_out, int out_size, void* d_ws, size_t ws_size,
                              hipStream_t stream) {
  const float* enc = (const float*)d_in[0];
  const float* dec = (const float*)d_in[1];
  const float* W1  = (const float*)d_in[2];
  const float* b1  = (const float*)d_in[3];
  const float* W2  = (const float*)d_in[4];
  const float* b2  = (const float*)d_in[5];
  float* out = (float*)d_out;
  char* ws = (char*)d_ws;

  float* pe = (float*)ws;                                   // 2 MB
  float* pd = (float*)(ws + (2u << 20));                    // 0.8 MB
  unsigned short* w2g = (unsigned short*)(ws + (3u << 20)); // 1 MB, fragged

  prep_kernel<<<dim3(55, 8), 256, 0, stream>>>(enc, dec, W1, W2, pe, pd, w2g);
  fused_joint_kernel<<<MROWS / 128, 512, 0, stream>>>(pe, pd, b1, w2g, b2, out);
}

// Round 18
// 243.949 us; speedup vs baseline: 1.7002x; 1.7002x over previous
//
#include <hip/hip_runtime.h>
#include <hip/hip_bf16.h>

// Problem constants
#define NB 4
#define NT 256
#define NU 100
#define NH 512      // H_ENC = H_DEC = 512
#define NI 512      // INNER
#define NV 1024     // VOCAB
#define MROWS (NB * NT * NU)   // 102400 joint rows

typedef __attribute__((ext_vector_type(4))) float f32x4;
typedef __attribute__((ext_vector_type(8))) __bf16 bf16x8;

// round-to-nearest-even f32 -> bf16 bits
static __device__ __forceinline__ unsigned int f2bf(float f) {
  unsigned int u = __float_as_uint(f);
  return (u + 0x7FFFu + ((u >> 16) & 1u)) >> 16;
}

// tanh(x) = 1 - 2/(1+e^{2x})
static __device__ __forceinline__ float fast_tanh(float x) {
  float e = __expf(2.f * x);
  return 1.f - 2.f * __builtin_amdgcn_rcpf(1.f + e);
}

// packed RNE f32x2 -> bf16x2 (single instruction)
static __device__ __forceinline__ unsigned int cvt_pk_bf16(float lo, float hi) {
  unsigned int r;
  asm("v_cvt_pk_bf16_f32 %0, %1, %2" : "=v"(r) : "v"(lo), "v"(hi));
  return r;
}

// ---------------------------------------------------------------------------
// Merged prep kernel. Grid (55, 8):
//  bx < 23: projections  pe[r][i] = enc[r][:] . W1[i][0:512]     (r < 1024)
//                        pd[r][i] = dec[r][:] . W1[i][512:1024]  (r < 400)
//  bx >= 23: W2 f32 -> bf16 pre-fragged for 16x16x32 B operands, BK=32:
//    chunk c (16B) = [nt 4][kt 16][cb 16][lq 4][lr 16] ->
//      col = nt*256 + cb*16 + lr,  k = kt*32 + lq*8
// ---------------------------------------------------------------------------
__global__ __launch_bounds__(256) void prep_kernel(
    const float* __restrict__ enc, const float* __restrict__ dec,
    const float* __restrict__ W1, const float* __restrict__ W2,
    float* __restrict__ pe, float* __restrict__ pd,
    unsigned short* __restrict__ w2f) {
  const int bx = blockIdx.x;
  const int tx = threadIdx.x;
  if (bx >= 23) {
    int c = ((bx - 23) * 8 + blockIdx.y) * 256 + tx;  // 65536 chunks
    int lr = c & 15, lq = (c >> 4) & 3;
    int cb = (c >> 6) & 15, kt = (c >> 10) & 15, nt = (c >> 14) & 3;
    int v = nt * 256 + cb * 16 + lr;
    int k = kt * 32 + lq * 8;
    const float* src = W2 + (size_t)v * NI + k;
    float4 a = *(const float4*)src;
    float4 b = *(const float4*)(src + 4);
    uint4 o;
    o.x = f2bf(a.x) | (f2bf(a.y) << 16);
    o.y = f2bf(a.z) | (f2bf(a.w) << 16);
    o.z = f2bf(b.x) | (f2bf(b.y) << 16);
    o.w = f2bf(b.z) | (f2bf(b.w) << 16);
    *(uint4*)(w2f + (size_t)c * 8) = o;
    return;
  }
  __shared__ float As[64][17];
  __shared__ float Bs[64][17];
  const float* A;
  float* P;
  int Mrows, colOff, row0;
  if (bx < 16) { A = enc; P = pe; Mrows = NB * NT; colOff = 0;  row0 = bx * 64; }
  else         { A = dec; P = pd; Mrows = NB * NU; colOff = NH; row0 = (bx - 16) * 64; }
  const int col0 = blockIdx.y * 64;
  const int tr = tx >> 4, tc = tx & 15;
  const int lr = tx >> 2, lc = (tx & 3) * 4;
  float acc[4][4] = {};
  for (int k0 = 0; k0 < NH; k0 += 16) {
    float4 av = make_float4(0.f, 0.f, 0.f, 0.f);
    if (row0 + lr < Mrows)
      av = *(const float4*)(A + (size_t)(row0 + lr) * NH + k0 + lc);
    float4 bv = *(const float4*)(W1 + (size_t)(col0 + lr) * (NH + NH) + colOff + k0 + lc);
    As[lr][lc] = av.x; As[lr][lc + 1] = av.y; As[lr][lc + 2] = av.z; As[lr][lc + 3] = av.w;
    Bs[lr][lc] = bv.x; Bs[lr][lc + 1] = bv.y; Bs[lr][lc + 2] = bv.z; Bs[lr][lc + 3] = bv.w;
    __syncthreads();
#pragma unroll
    for (int kk = 0; kk < 16; ++kk) {
      float a4[4], b4[4];
#pragma unroll
      for (int i = 0; i < 4; ++i) { a4[i] = As[tr * 4 + i][kk]; b4[i] = Bs[tc * 4 + i][kk]; }
#pragma unroll
      for (int i = 0; i < 4; ++i)
#pragma unroll
        for (int j = 0; j < 4; ++j) acc[i][j] = fmaf(a4[i], b4[j], acc[i][j]);
    }
    __syncthreads();
  }
#pragma unroll
  for (int i = 0; i < 4; ++i) {
    int r = row0 + tr * 4 + i;
    if (r < Mrows) {
#pragma unroll
      for (int j = 0; j < 4; ++j)
        P[(size_t)r * NI + col0 + tc * 4 + j] = acc[i][j];
    }
  }
}

// ---------------------------------------------------------------------------
// Fused joint GEMM: R12 structure with doubled wave-M.
// Block: 512 thr / 8 waves (2M x 4N), 128 rows x FULL 1024 vocab.
// Wave tile 64 rows x 64 cols (acc[4][4] 16x16 tiles = 64 VGPR).
//   -> aggregate B-fragment L2 traffic = 102400/64 MB = 1.6 GB (half of R12),
//      store pattern stays 256B-sector-clean per wave (R17's regression was
//      128B segments -> RMW amplification; avoided here).
// Phase 0: A panel (128 x 512) = tanh(pe+pd+b1) -> 128 KB LDS, granule
//   swizzle g8 ^ (row&7) (2-way quarter-wave = free). ONE barrier total.
// K-loop: 64 steps of BK=32 (np = g>>4 panel, kt = g&15), even/odd register
//   B sets (4 x bf16x8 each), use-then-reload: LOADB(bB,g+1); COMPUTE(bA,g);
//   LOADB(bA,g+2); COMPUTE(bB,g+1). Use trails load by >=16 MFMA (~L2 lat).
// Epilogue per panel (kt==15): +b2, fp32 stores; each row receives its full
//   256B sector from 4 consecutive stores within one wave.
// ---------------------------------------------------------------------------
__global__ __launch_bounds__(512, 2) void fused_joint_kernel(
    const float* __restrict__ pe, const float* __restrict__ pd,
    const float* __restrict__ b1, const unsigned short* __restrict__ w2f,
    const float* __restrict__ b2, float* __restrict__ out) {
  __shared__ unsigned char ldsA[131072];   // 128 rows x 512 k bf16, swizzled
  const int tx = threadIdx.x;
  const int R0 = blockIdx.x * 128;
  const int lane = tx & 63, wid = tx >> 6;
  const int wr = wid >> 2, wc = wid & 3;   // 2M x 4N; wave tile 64 x 64
  const int lr = lane & 15, lq = lane >> 4;

  // B fragment base: chunk = G*1024 + (wc*4+nf)*64 + lq*16 + lr (16B each)
  const unsigned short* w2base = w2f + ((size_t)(wc * 4) * 64 + lq * 16 + lr) * 8;
#define LOADB(DST, G) do {                                                    \
    const unsigned short* s_ = w2base + ((size_t)(G) << 13);                  \
    DST##0 = *(const bf16x8*)(s_);                                            \
    DST##1 = *(const bf16x8*)(s_ + 512);                                      \
    DST##2 = *(const bf16x8*)(s_ + 1024);                                     \
    DST##3 = *(const bf16x8*)(s_ + 1536);                                     \
  } while (0)

  bf16x8 bA0, bA1, bA2, bA3, bB0, bB1, bB2, bB3;
  LOADB(bA, 0);                            // in flight through phase 0

  // ---- Phase 0: A panel (128 x 512) = tanh(pe+pd+b1) -> ldsA ----
#pragma unroll 2
  for (int pass = 0; pass < 16; ++pass) {
    int idx = pass * 512 + tx;             // 8192 granules of 8 elems
    int row = idx >> 6;                    // 0..127
    int g8 = idx & 63;                     // granule within row
    int i0 = g8 * 8;
    int grow = R0 + row;
    int b = grow / (NT * NU);
    int rem = grow - b * (NT * NU);
    int t = rem / NU;
    int u = rem - t * NU;
    const float* peP = pe + (size_t)(b * NT + t) * NI + i0;
    const float* pdP = pd + (size_t)(b * NU + u) * NI + i0;
    float4 p0 = *(const float4*)peP, p1 = *(const float4*)(peP + 4);
    float4 q0 = *(const float4*)pdP, q1 = *(const float4*)(pdP + 4);
    float4 c0 = *(const float4*)(b1 + i0), c1 = *(const float4*)(b1 + i0 + 4);
    uint4 pk;
    pk.x = cvt_pk_bf16(fast_tanh(p0.x + q0.x + c0.x), fast_tanh(p0.y + q0.y + c0.y));
    pk.y = cvt_pk_bf16(fast_tanh(p0.z + q0.z + c0.z), fast_tanh(p0.w + q0.w + c0.w));
    pk.z = cvt_pk_bf16(fast_tanh(p1.x + q1.x + c1.x), fast_tanh(p1.y + q1.y + c1.y));
    pk.w = cvt_pk_bf16(fast_tanh(p1.z + q1.z + c1.z), fast_tanh(p1.w + q1.w + c1.w));
    *(uint4*)(ldsA + row * 1024 + ((g8 ^ (row & 7)) << 4)) = pk;
  }
  __syncthreads();                         // the ONLY barrier

  f32x4 acc[4][4];
#pragma unroll
  for (int mf = 0; mf < 4; ++mf)
#pragma unroll
    for (int nf = 0; nf < 4; ++nf)
#pragma unroll
      for (int z = 0; z < 4; ++z) acc[mf][nf][z] = 0.f;

#define COMPUTE(BV, G) do {                                                   \
    const int kt_ = (G) & 15;                                                 \
    bf16x8 af_[4];                                                            \
    _Pragma("unroll")                                                         \
    for (int mf = 0; mf < 4; ++mf) {                                          \
      int row_ = wr * 64 + mf * 16 + lr;                                      \
      af_[mf] = *(const bf16x8*)(ldsA + row_ * 1024 +                         \
                                 (((kt_ * 4 + lq) ^ (lr & 7)) << 4));         \
    }                                                                         \
    __builtin_amdgcn_s_setprio(1);                                            \
    _Pragma("unroll")                                                         \
    for (int mf = 0; mf < 4; ++mf) {                                          \
      acc[mf][0] = __builtin_amdgcn_mfma_f32_16x16x32_bf16(af_[mf], BV##0, acc[mf][0], 0, 0, 0); \
      acc[mf][1] = __builtin_amdgcn_mfma_f32_16x16x32_bf16(af_[mf], BV##1, acc[mf][1], 0, 0, 0); \
      acc[mf][2] = __builtin_amdgcn_mfma_f32_16x16x32_bf16(af_[mf], BV##2, acc[mf][2], 0, 0, 0); \
      acc[mf][3] = __builtin_amdgcn_mfma_f32_16x16x32_bf16(af_[mf], BV##3, acc[mf][3], 0, 0, 0); \
    }                                                                         \
    __builtin_amdgcn_s_setprio(0);                                            \
    if (kt_ == 15) {                                                          \
      const int np_ = (G) >> 4;                                               \
      _Pragma("unroll")                                                       \
      for (int nf = 0; nf < 4; ++nf) {                                        \
        int col_ = np_ * 256 + wc * 64 + nf * 16 + lr;                        \
        float bb_ = b2[col_];                                                 \
        _Pragma("unroll")                                                     \
        for (int mf = 0; mf < 4; ++mf) {                                      \
          _Pragma("unroll")                                                   \
          for (int j = 0; j < 4; ++j) {                                       \
            int grow_ = R0 + wr * 64 + mf * 16 + lq * 4 + j;                  \
            out[(size_t)grow_ * NV + col_] = acc[mf][nf][j] + bb_;            \
            acc[mf][nf][j] = 0.f;                                             \
          }                                                                   \
        }                                                                     \
      }                                                                       \
    }                                                                         \
  } while (0)

  for (int g = 0; g < 64; g += 2) {
    LOADB(bB, g + 1);                      // prefetch odd step
    COMPUTE(bA, g);
    if (g + 2 < 64) LOADB(bA, g + 2);      // prefetch next even step
    COMPUTE(bB, g + 1);
  }
#undef COMPUTE
#undef LOADB
}

extern "C" void kernel_launch(void* const* d_in, const int* in_sizes, int n_in,
                              void* d_out, int out_size, void* d_ws, size_t ws_size,
                              hipStream_t stream) {
  const float* enc = (const float*)d_in[0];
  const float* dec = (const float*)d_in[1];
  const float* W1  = (const float*)d_in[2];
  const float* b1  = (const float*)d_in[3];
  const float* W2  = (const float*)d_in[4];
  const float* b2  = (const float*)d_in[5];
  float* out = (float*)d_out;
  char* ws = (char*)d_ws;

  float* pe = (float*)ws;                                   // 2 MB
  float* pd = (float*)(ws + (2u << 20));                    // 0.8 MB
  unsigned short* w2f = (unsigned short*)(ws + (3u << 20)); // 1 MB, fragged

  prep_kernel<<<dim3(55, 8), 256, 0, stream>>>(enc, dec, W1, W2, pe, pd, w2f);
  fused_joint_kernel<<<MROWS / 128, 512, 0, stream>>>(pe, pd, b1, w2f, b2, out);
}

// Round 19
// 239.359 us; speedup vs baseline: 1.7328x; 1.0192x over previous
//
#include <hip/hip_runtime.h>
#include <hip/hip_bf16.h>

// Problem constants
#define NB 4
#define NT 256
#define NU 100
#define NH 512      // H_ENC = H_DEC = 512
#define NI 512      // INNER
#define NV 1024     // VOCAB
#define MROWS (NB * NT * NU)   // 102400 joint rows

typedef __attribute__((ext_vector_type(4))) float f32x4;
typedef __attribute__((ext_vector_type(8))) __bf16 bf16x8;

// round-to-nearest-even f32 -> bf16 bits
static __device__ __forceinline__ unsigned int f2bf(float f) {
  unsigned int u = __float_as_uint(f);
  return (u + 0x7FFFu + ((u >> 16) & 1u)) >> 16;
}

// tanh(x) = 1 - 2/(1+e^{2x})
static __device__ __forceinline__ float fast_tanh(float x) {
  float e = __expf(2.f * x);
  return 1.f - 2.f * __builtin_amdgcn_rcpf(1.f + e);
}

// packed RNE f32x2 -> bf16x2 (single instruction)
static __device__ __forceinline__ unsigned int cvt_pk_bf16(float lo, float hi) {
  unsigned int r;
  asm("v_cvt_pk_bf16_f32 %0, %1, %2" : "=v"(r) : "v"(lo), "v"(hi));
  return r;
}

// ---------------------------------------------------------------------------
// Merged prep kernel. Grid (55, 8):
//  bx < 23: projections  pe[r][i] = enc[r][:] . W1[i][0:512]     (r < 1024)
//                        pd[r][i] = dec[r][:] . W1[i][512:1024]  (r < 400)
//  bx >= 23: W2 f32 -> bf16 pre-fragged for 16x16x32 B operands, BK=32:
//    chunk c (16B) = [nt 4][kt 16][cb 16][lq 4][lr 16] ->
//      col = nt*256 + cb*16 + lr,  k = kt*32 + lq*8
// ---------------------------------------------------------------------------
__global__ __launch_bounds__(256) void prep_kernel(
    const float* __restrict__ enc, const float* __restrict__ dec,
    const float* __restrict__ W1, const float* __restrict__ W2,
    float* __restrict__ pe, float* __restrict__ pd,
    unsigned short* __restrict__ w2f) {
  const int bx = blockIdx.x;
  const int tx = threadIdx.x;
  if (bx >= 23) {
    int c = ((bx - 23) * 8 + blockIdx.y) * 256 + tx;  // 65536 chunks
    int lr = c & 15, lq = (c >> 4) & 3;
    int cb = (c >> 6) & 15, kt = (c >> 10) & 15, nt = (c >> 14) & 3;
    int v = nt * 256 + cb * 16 + lr;
    int k = kt * 32 + lq * 8;
    const float* src = W2 + (size_t)v * NI + k;
    float4 a = *(const float4*)src;
    float4 b = *(const float4*)(src + 4);
    uint4 o;
    o.x = f2bf(a.x) | (f2bf(a.y) << 16);
    o.y = f2bf(a.z) | (f2bf(a.w) << 16);
    o.z = f2bf(b.x) | (f2bf(b.y) << 16);
    o.w = f2bf(b.z) | (f2bf(b.w) << 16);
    *(uint4*)(w2f + (size_t)c * 8) = o;
    return;
  }
  __shared__ float As[64][17];
  __shared__ float Bs[64][17];
  const float* A;
  float* P;
  int Mrows, colOff, row0;
  if (bx < 16) { A = enc; P = pe; Mrows = NB * NT; colOff = 0;  row0 = bx * 64; }
  else         { A = dec; P = pd; Mrows = NB * NU; colOff = NH; row0 = (bx - 16) * 64; }
  const int col0 = blockIdx.y * 64;
  const int tr = tx >> 4, tc = tx & 15;
  const int lr = tx >> 2, lc = (tx & 3) * 4;
  float acc[4][4] = {};
  for (int k0 = 0; k0 < NH; k0 += 16) {
    float4 av = make_float4(0.f, 0.f, 0.f, 0.f);
    if (row0 + lr < Mrows)
      av = *(const float4*)(A + (size_t)(row0 + lr) * NH + k0 + lc);
    float4 bv = *(const float4*)(W1 + (size_t)(col0 + lr) * (NH + NH) + colOff + k0 + lc);
    As[lr][lc] = av.x; As[lr][lc + 1] = av.y; As[lr][lc + 2] = av.z; As[lr][lc + 3] = av.w;
    Bs[lr][lc] = bv.x; Bs[lr][lc + 1] = bv.y; Bs[lr][lc + 2] = bv.z; Bs[lr][lc + 3] = bv.w;
    __syncthreads();
#pragma unroll
    for (int kk = 0; kk < 16; ++kk) {
      float a4[4], b4[4];
#pragma unroll
      for (int i = 0; i < 4; ++i) { a4[i] = As[tr * 4 + i][kk]; b4[i] = Bs[tc * 4 + i][kk]; }
#pragma unroll
      for (int i = 0; i < 4; ++i)
#pragma unroll
        for (int j = 0; j < 4; ++j) acc[i][j] = fmaf(a4[i], b4[j], acc[i][j]);
    }
    __syncthreads();
  }
#pragma unroll
  for (int i = 0; i < 4; ++i) {
    int r = row0 + tr * 4 + i;
    if (r < Mrows) {
#pragma unroll
      for (int j = 0; j < 4; ++j)
        P[(size_t)r * NI + col0 + tc * 4 + j] = acc[i][j];
    }
  }
}

// ---------------------------------------------------------------------------
// Fused joint GEMM (R12 champion + A-fragment software pipeline).
// Block: 512 thr / 8 waves (2M x 4N), 64 rows x FULL 1024 vocab.
// Wave tile 32 x 64 (acc[2][4] = 32 VGPR).
// Phase 0: A panel (64 x 512) = tanh(pe+pd+b1) -> 64 KB LDS (full K),
//   granule swizzle g8 ^ (row&7). ONE barrier total.
// K-loop: 64 steps of BK=32 (np = g>>4 panel, kt = g&15):
//   - B: even/odd register sets (4 x bf16x8), use-then-reload, reuse trails
//     reload by one full step (~2x8 MFMA under 4-way SIMD sharing).
//   - A: aC/aN named fragment pairs; LOADA(next) issued BEFORE MFMA(cur),
//     so the lgkmcnt wait lands >=8 MFMA after issue — LDS latency off the
//     critical path (this round's delta vs R12).
// launch_bounds(512,4): <=128 VGPR -> 4 waves/SIMD; 64 KB LDS -> 2 blocks/CU.
// Epilogue per vocab panel (kt==15): +b2, fp32 stores (256B-sector-clean),
//   re-zero acc.
// ---------------------------------------------------------------------------
__global__ __launch_bounds__(512, 4) void fused_joint_kernel(
    const float* __restrict__ pe, const float* __restrict__ pd,
    const float* __restrict__ b1, const unsigned short* __restrict__ w2f,
    const float* __restrict__ b2, float* __restrict__ out) {
  __shared__ unsigned char ldsA[65536];    // 64 rows x 512 k bf16, swizzled
  const int tx = threadIdx.x;
  const int R0 = blockIdx.x * 64;
  const int lane = tx & 63, wid = tx >> 6;
  const int wr = wid >> 2, wc = wid & 3;   // 2M x 4N; wave tile 32 x 64
  const int lr = lane & 15, lq = lane >> 4;

  // B fragment base: chunk = G*1024 + (wc*4+nf)*64 + lq*16 + lr (16B each)
  const unsigned short* w2base = w2f + ((size_t)(wc * 4) * 64 + lq * 16 + lr) * 8;
#define LOADB(DST, G) do {                                                    \
    const unsigned short* s_ = w2base + ((size_t)(G) << 13);                  \
    DST##0 = *(const bf16x8*)(s_);                                            \
    DST##1 = *(const bf16x8*)(s_ + 512);                                      \
    DST##2 = *(const bf16x8*)(s_ + 1024);                                     \
    DST##3 = *(const bf16x8*)(s_ + 1536);                                     \
  } while (0)

  bf16x8 bA0, bA1, bA2, bA3, bB0, bB1, bB2, bB3;
  LOADB(bA, 0);                            // in flight through phase 0

  // ---- Phase 0: A panel (64 x 512) = tanh(pe+pd+b1) -> ldsA ----
#pragma unroll 2
  for (int pass = 0; pass < 8; ++pass) {
    int idx = pass * 512 + tx;             // 4096 granules of 8 elems
    int row = idx >> 6;                    // 0..63
    int g8 = idx & 63;                     // granule within row
    int i0 = g8 * 8;
    int grow = R0 + row;
    int b = grow / (NT * NU);
    int rem = grow - b * (NT * NU);
    int t = rem / NU;
    int u = rem - t * NU;
    const float* peP = pe + (size_t)(b * NT + t) * NI + i0;
    const float* pdP = pd + (size_t)(b * NU + u) * NI + i0;
    float4 p0 = *(const float4*)peP, p1 = *(const float4*)(peP + 4);
    float4 q0 = *(const float4*)pdP, q1 = *(const float4*)(pdP + 4);
    float4 c0 = *(const float4*)(b1 + i0), c1 = *(const float4*)(b1 + i0 + 4);
    uint4 pk;
    pk.x = cvt_pk_bf16(fast_tanh(p0.x + q0.x + c0.x), fast_tanh(p0.y + q0.y + c0.y));
    pk.y = cvt_pk_bf16(fast_tanh(p0.z + q0.z + c0.z), fast_tanh(p0.w + q0.w + c0.w));
    pk.z = cvt_pk_bf16(fast_tanh(p1.x + q1.x + c1.x), fast_tanh(p1.y + q1.y + c1.y));
    pk.w = cvt_pk_bf16(fast_tanh(p1.z + q1.z + c1.z), fast_tanh(p1.w + q1.w + c1.w));
    *(uint4*)(ldsA + row * 1024 + ((g8 ^ (row & 7)) << 4)) = pk;
  }
  __syncthreads();                         // the ONLY barrier

  f32x4 acc[2][4];
#pragma unroll
  for (int mf = 0; mf < 2; ++mf)
#pragma unroll
    for (int nf = 0; nf < 4; ++nf)
#pragma unroll
      for (int z = 0; z < 4; ++z) acc[mf][nf][z] = 0.f;

  // A-fragment addressing (row&7 == lr&7 since rows differ by 16/32)
  const int aOff0 = (wr * 32 + lr) * 1024;        // mf = 0 row
  const int aOff1 = (wr * 32 + 16 + lr) * 1024;   // mf = 1 row
  const int rx = lr & 7;

#define LOADA(AF, G) do {                                                     \
    const int so_ = ((((G) & 15) * 4 + lq) ^ rx) << 4;                        \
    AF##0 = *(const bf16x8*)(ldsA + aOff0 + so_);                             \
    AF##1 = *(const bf16x8*)(ldsA + aOff1 + so_);                             \
  } while (0)

#define MFMA8(AF, BV, G) do {                                                 \
    __builtin_amdgcn_s_setprio(1);                                            \
    acc[0][0] = __builtin_amdgcn_mfma_f32_16x16x32_bf16(AF##0, BV##0, acc[0][0], 0, 0, 0); \
    acc[0][1] = __builtin_amdgcn_mfma_f32_16x16x32_bf16(AF##0, BV##1, acc[0][1], 0, 0, 0); \
    acc[0][2] = __builtin_amdgcn_mfma_f32_16x16x32_bf16(AF##0, BV##2, acc[0][2], 0, 0, 0); \
    acc[0][3] = __builtin_amdgcn_mfma_f32_16x16x32_bf16(AF##0, BV##3, acc[0][3], 0, 0, 0); \
    acc[1][0] = __builtin_amdgcn_mfma_f32_16x16x32_bf16(AF##1, BV##0, acc[1][0], 0, 0, 0); \
    acc[1][1] = __builtin_amdgcn_mfma_f32_16x16x32_bf16(AF##1, BV##1, acc[1][1], 0, 0, 0); \
    acc[1][2] = __builtin_amdgcn_mfma_f32_16x16x32_bf16(AF##1, BV##2, acc[1][2], 0, 0, 0); \
    acc[1][3] = __builtin_amdgcn_mfma_f32_16x16x32_bf16(AF##1, BV##3, acc[1][3], 0, 0, 0); \
    __builtin_amdgcn_s_setprio(0);                                            \
    if (((G) & 15) == 15) {                                                   \
      const int np_ = (G) >> 4;                                               \
      _Pragma("unroll")                                                       \
      for (int nf = 0; nf < 4; ++nf) {                                        \
        int col_ = np_ * 256 + wc * 64 + nf * 16 + lr;                        \
        float bb_ = b2[col_];                                                 \
        _Pragma("unroll")                                                     \
        for (int mf = 0; mf < 2; ++mf) {                                      \
          _Pragma("unroll")                                                   \
          for (int j = 0; j < 4; ++j) {                                       \
            int grow_ = R0 + wr * 32 + mf * 16 + lq * 4 + j;                  \
            out[(size_t)grow_ * NV + col_] = acc[mf][nf][j] + bb_;            \
            acc[mf][nf][j] = 0.f;                                             \
          }                                                                   \
        }                                                                     \
      }                                                                       \
    }                                                                         \
  } while (0)

  bf16x8 aC0, aC1, aN0, aN1;
  LOADA(aC, 0);                            // step-0 fragments

  for (int g = 0; g < 64; g += 2) {
    LOADB(bB, g + 1);                      // B for odd step (used next)
    LOADA(aN, g + 1);                      // A for odd step, ahead of MFMAs
    MFMA8(aC, bA, g);                      // even step (+ epilogue if kt==15)
    if (g + 2 < 64) {
      LOADB(bA, g + 2);                    // B for next even step
      LOADA(aC, g + 2);                    // A for next even step
    }
    MFMA8(aN, bB, g + 1);                  // odd step (+ epilogue if kt==15)
  }
#undef MFMA8
#undef LOADA
#undef LOADB
}

extern "C" void kernel_launch(void* const* d_in, const int* in_sizes, int n_in,
                              void* d_out, int out_size, void* d_ws, size_t ws_size,
                              hipStream_t stream) {
  const float* enc = (const float*)d_in[0];
  const float* dec = (const float*)d_in[1];
  const float* W1  = (const float*)d_in[2];
  const float* b1  = (const float*)d_in[3];
  const float* W2  = (const float*)d_in[4];
  const float* b2  = (const float*)d_in[5];
  float* out = (float*)d_out;
  char* ws = (char*)d_ws;

  float* pe = (float*)ws;                                   // 2 MB
  float* pd = (float*)(ws + (2u << 20));                    // 0.8 MB
  unsigned short* w2f = (unsigned short*)(ws + (3u << 20)); // 1 MB, fragged

  prep_kernel<<<dim3(55, 8), 256, 0, stream>>>(enc, dec, W1, W2, pe, pd, w2f);
  fused_joint_kernel<<<MROWS / 64, 512, 0, stream>>>(pe, pd, b1, w2f, b2, out);
}